// Round 12
// baseline (142.659 us; speedup 1.0000x reference)
//
#include <hip/hip_runtime.h>
#include <hip/hip_bf16.h>

// ---------------------------------------------------------------------------
// total = CE + 0.05*MSE + 0.05*div + 0.05*sim + 0.05*cov
// Round 12: R11 champion (2-tile dist, counted vmcnt(12), NT 8-deep MSE)
// + final combine folded into fused_kernel via last-block pattern
//   (threadfence + device atomic counter; 128-thread parallel reduction).
// Removes the final_kernel launch gap + serial 128-load loop.
// ---------------------------------------------------------------------------

constexpr float FEPS = 1e-12f;
constexpr float DMIN = 1.0f;

#define NB_DIST 256
#define NB_MSE  1024
#define NB_CE   256
#define NB_DIV  128
#define GRID_TOTAL (NB_DIST + NB_MSE + NB_CE + NB_DIV)

typedef unsigned short ushort_t;
typedef __attribute__((ext_vector_type(8))) short bf16x8;
typedef __attribute__((ext_vector_type(8))) unsigned short u16x8;
typedef __attribute__((ext_vector_type(4))) unsigned short u16x4;
typedef __attribute__((ext_vector_type(16))) float f32x16;
typedef __attribute__((ext_vector_type(4))) float f32x4;

typedef __attribute__((address_space(1))) const void gvoid_t;
typedef __attribute__((address_space(3))) void lvoid_t;

__device__ __forceinline__ unsigned short f2b(float f) {
    unsigned u = __float_as_uint(f);
    u += 0x7FFFu + ((u >> 16) & 1u);   // RNE to bf16
    return (unsigned short)(u >> 16);
}

union SmemU {
    struct {
        char     As[2 * 8192];     // 2 tiles x 64 rows x 128B bf16, swizzled
        char     Bs[2 * 16384];    // dbuf: 128 protos x 128B bf16 (swz via src)
        float    rown[128];        // [tile*64 + row]
        float    pn[128];
        unsigned rowmin[128];
        unsigned colmin[128];
    } dist;                        // 51200 B -> 3 blocks/CU
    struct { float pp[512]; float spp; float sred[4]; } div;
    struct { float sred[4]; } red;
};

// -------- proto fp32 -> bf16 (linear [p][k]) + norms + init -----------------
__global__ __launch_bounds__(128) void conv_kernel(const float* __restrict__ proto,
                                                   ushort_t* __restrict__ pB,
                                                   float* __restrict__ pnorm,
                                                   float* __restrict__ ws,
                                                   unsigned* __restrict__ proto_min,
                                                   unsigned* __restrict__ donec) {
    int p = blockIdx.x, q = threadIdx.x;
    if (q == 0) proto_min[p] = 0x7F7F7F7Fu;
    if (p == 0 && q < 4) ws[q] = 0.f;
    if (p == 0 && q == 4) donec[0] = 0u;
    float4 v = ((const float4*)(proto + (size_t)p * 512))[q];
    u16x4 o = { f2b(v.x), f2b(v.y), f2b(v.z), f2b(v.w) };
    *(u16x4*)(pB + (size_t)p * 512 + q * 4) = o;
    float s = v.x * v.x + v.y * v.y + v.z * v.z + v.w * v.w;
    #pragma unroll
    for (int off = 32; off; off >>= 1) s += __shfl_xor(s, off);
    __shared__ float sr[2];
    if ((q & 63) == 0) sr[q >> 6] = s;
    __syncthreads();
    if (q == 0) pnorm[p] = sr[0] + sr[1];
}

// ---------------- dist body FAST: 2-tile interleaved, counted vmcnt ---------
__device__ __forceinline__ void dist_body_fast(SmemU& sm, int bid,
                                               const float* __restrict__ emb,
                                               const ushort_t* __restrict__ pB,
                                               const float* __restrict__ pnormG,
                                               unsigned* __restrict__ proto_min,
                                               float* __restrict__ cov_out) {
    char*     AsB     = sm.dist.As;
    char*     BsB     = sm.dist.Bs;
    float*    rownL   = sm.dist.rown;
    float*    pnL     = sm.dist.pn;
    unsigned* rowminL = sm.dist.rowmin;
    unsigned* colminL = sm.dist.colmin;

    const int t  = threadIdx.x;
    const int m0 = bid * 128;

    if (t < 128) {
        rownL[t] = 0.f; rowminL[t] = 0x7F7F7F7Fu;
        colminL[t] = 0x7F7F7F7Fu; pnL[t] = pnormG[t];
    }

    int aidx[4], rowi[4], swzi[4];
    const float4* embF4 = (const float4*)emb;
    #pragma unroll
    for (int i = 0; i < 4; ++i) {
        int flat = i * 256 + t;
        int row = flat >> 4, colq = flat & 15;
        rowi[i] = row;
        aidx[i] = (m0 + row) * 128 + colq;
        swzi[i] = row * 128 + ((((colq >> 1) ^ (row & 7)) << 4) | ((colq & 1) << 3));
    }

    const ushort_t* bsrcp[4];
    char* bdstW[4];
    #pragma unroll
    for (int i = 0; i < 4; ++i) {
        int f = i * 256 + t;
        int pr = f >> 3, gb = f & 7;
        bsrcp[i] = pB + pr * 512 + ((gb ^ (pr & 7)) << 3);
        bdstW[i] = BsB + (size_t)(i * 256 + (t & ~63)) * 16;   // wave-uniform
    }

    const int lane = t & 63, wv = t >> 6;
    const int wr = wv >> 1, wc = wv & 1;
    const int lo = lane & 31, hi = lane >> 5;
    const int arow = wr * 32 + lo;
    const int arz  = arow & 7;
    const int p0 = wc * 64 + lo, p1 = p0 + 32;
    const int pz = p0 & 7;
    const char* Ar0 = AsB + arow * 128;
    const char* Ar1 = AsB + 8192 + arow * 128;
    const char* Br0 = BsB + p0 * 128;
    const char* Br1 = BsB + p1 * 128;

    __builtin_amdgcn_global_load_lds((gvoid_t*)(bsrcp[0]), (lvoid_t*)bdstW[0], 16, 0, 0);
    __builtin_amdgcn_global_load_lds((gvoid_t*)(bsrcp[1]), (lvoid_t*)bdstW[1], 16, 0, 0);
    __builtin_amdgcn_global_load_lds((gvoid_t*)(bsrcp[2]), (lvoid_t*)bdstW[2], 16, 0, 0);
    __builtin_amdgcn_global_load_lds((gvoid_t*)(bsrcp[3]), (lvoid_t*)bdstW[3], 16, 0, 0);
    float4 a00 = embF4[aidx[0]],        a01 = embF4[aidx[1]],
           a02 = embF4[aidx[2]],        a03 = embF4[aidx[3]];
    float4 a10 = embF4[aidx[0] + 8192], a11 = embF4[aidx[1] + 8192],
           a12 = embF4[aidx[2] + 8192], a13 = embF4[aidx[3] + 8192];
    float rn00 = 0.f, rn01 = 0.f, rn02 = 0.f, rn03 = 0.f;
    float rn10 = 0.f, rn11 = 0.f, rn12 = 0.f, rn13 = 0.f;
    f32x16 acc00 = {}, acc01 = {}, acc10 = {}, acc11 = {};
    asm volatile("s_waitcnt lgkmcnt(0)" ::: "memory");
    __builtin_amdgcn_s_barrier();
    __builtin_amdgcn_sched_barrier(0);

#define FNORM(v, rn) rn = fmaf(v.x, v.x, rn); rn = fmaf(v.y, v.y, rn);         \
                     rn = fmaf(v.z, v.z, rn); rn = fmaf(v.w, v.w, rn);
#define AWRITE(v, base, i) { u16x4 u = { f2b(v.x), f2b(v.y), f2b(v.z), f2b(v.w) }; \
                             *(u16x4*)((base) + swzi[i]) = u; }
#define DIST_CHUNK(c, WAITN)                                                   \
    {                                                                          \
        if ((c) < 7) {                                                         \
            const int kc1 = ((c) + 1) * 64;                                    \
            const int bo1 = (((c) + 1) & 1) * 16384;                           \
            __builtin_amdgcn_global_load_lds((gvoid_t*)(bsrcp[0] + kc1),       \
                (lvoid_t*)(bdstW[0] + bo1), 16, 0, 0);                         \
            __builtin_amdgcn_global_load_lds((gvoid_t*)(bsrcp[1] + kc1),       \
                (lvoid_t*)(bdstW[1] + bo1), 16, 0, 0);                         \
            __builtin_amdgcn_global_load_lds((gvoid_t*)(bsrcp[2] + kc1),       \
                (lvoid_t*)(bdstW[2] + bo1), 16, 0, 0);                         \
            __builtin_amdgcn_global_load_lds((gvoid_t*)(bsrcp[3] + kc1),       \
                (lvoid_t*)(bdstW[3] + bo1), 16, 0, 0);                         \
        }                                                                      \
        __builtin_amdgcn_sched_barrier(0);                                     \
        FNORM(a00, rn00) FNORM(a01, rn01) FNORM(a02, rn02) FNORM(a03, rn03)    \
        FNORM(a10, rn10) FNORM(a11, rn11) FNORM(a12, rn12) FNORM(a13, rn13)    \
        AWRITE(a00, AsB, 0) AWRITE(a01, AsB, 1)                                \
        AWRITE(a02, AsB, 2) AWRITE(a03, AsB, 3)                                \
        AWRITE(a10, AsB + 8192, 0) AWRITE(a11, AsB + 8192, 1)                  \
        AWRITE(a12, AsB + 8192, 2) AWRITE(a13, AsB + 8192, 3)                  \
        if ((c) < 7) {                                                         \
            const int kn = ((c) + 1) * 16;                                     \
            a00 = embF4[aidx[0] + kn];        a01 = embF4[aidx[1] + kn];       \
            a02 = embF4[aidx[2] + kn];        a03 = embF4[aidx[3] + kn];       \
            a10 = embF4[aidx[0] + 8192 + kn]; a11 = embF4[aidx[1] + 8192 + kn];\
            a12 = embF4[aidx[2] + 8192 + kn]; a13 = embF4[aidx[3] + 8192 + kn];\
        }                                                                      \
        __builtin_amdgcn_sched_barrier(0);                                     \
        asm volatile("s_waitcnt vmcnt(" #WAITN ")" ::: "memory");              \
        asm volatile("s_waitcnt lgkmcnt(0)" ::: "memory");                     \
        __builtin_amdgcn_s_barrier();                                          \
        __builtin_amdgcn_sched_barrier(0);                                     \
        {                                                                      \
            const int bo = ((c) & 1) * 16384;                                  \
            _Pragma("unroll")                                                  \
            for (int s = 0; s < 4; ++s) {                                      \
                const int g = (s * 2 + hi);                                    \
                bf16x8 af0 = *(const bf16x8*)(Ar0 + ((g ^ arz) << 4));         \
                bf16x8 af1 = *(const bf16x8*)(Ar1 + ((g ^ arz) << 4));         \
                bf16x8 b0  = *(const bf16x8*)(Br0 + bo + ((g ^ pz) << 4));     \
                bf16x8 b1  = *(const bf16x8*)(Br1 + bo + ((g ^ pz) << 4));     \
                acc00 = __builtin_amdgcn_mfma_f32_32x32x16_bf16(af0, b0, acc00, 0,0,0); \
                acc01 = __builtin_amdgcn_mfma_f32_32x32x16_bf16(af0, b1, acc01, 0,0,0); \
                acc10 = __builtin_amdgcn_mfma_f32_32x32x16_bf16(af1, b0, acc10, 0,0,0); \
                acc11 = __builtin_amdgcn_mfma_f32_32x32x16_bf16(af1, b1, acc11, 0,0,0); \
            }                                                                  \
        }                                                                      \
        asm volatile("s_waitcnt lgkmcnt(0)" ::: "memory");                     \
        __builtin_amdgcn_s_barrier();                                          \
        __builtin_amdgcn_sched_barrier(0);                                     \
    }

    DIST_CHUNK(0, 12)
    DIST_CHUNK(1, 12)
    DIST_CHUNK(2, 12)
    DIST_CHUNK(3, 12)
    DIST_CHUNK(4, 12)
    DIST_CHUNK(5, 12)
    DIST_CHUNK(6, 12)
    DIST_CHUNK(7, 0)
#undef DIST_CHUNK
#undef AWRITE
#undef FNORM

    atomicAdd(&rownL[rowi[0]], rn00);
    atomicAdd(&rownL[rowi[1]], rn01);
    atomicAdd(&rownL[rowi[2]], rn02);
    atomicAdd(&rownL[rowi[3]], rn03);
    atomicAdd(&rownL[64 + rowi[0]], rn10);
    atomicAdd(&rownL[64 + rowi[1]], rn11);
    atomicAdd(&rownL[64 + rowi[2]], rn12);
    atomicAdd(&rownL[64 + rowi[3]], rn13);
    __syncthreads();

    const float pn0 = pnL[p0], pn1 = pnL[p1];
    float cmin0 = 3.0e38f, cmin1 = 3.0e38f;
    #pragma unroll
    for (int r = 0; r < 16; ++r) {
        const int row = wr * 32 + (r & 3) + 8 * (r >> 2) + 4 * hi;
        const float nx0 = rownL[row];
        const float nx1 = rownL[64 + row];
        float d00 = sqrtf(fmaxf(nx0 + pn0 - 2.f * acc00[r], FEPS));
        float d01 = sqrtf(fmaxf(nx0 + pn1 - 2.f * acc01[r], FEPS));
        float d10 = sqrtf(fmaxf(nx1 + pn0 - 2.f * acc10[r], FEPS));
        float d11 = sqrtf(fmaxf(nx1 + pn1 - 2.f * acc11[r], FEPS));
        cmin0 = fminf(cmin0, fminf(d00, d10));
        cmin1 = fminf(cmin1, fminf(d01, d11));
        atomicMin(&rowminL[row],      __float_as_uint(fminf(d00, d01)));
        atomicMin(&rowminL[64 + row], __float_as_uint(fminf(d10, d11)));
    }
    atomicMin(&colminL[p0], __float_as_uint(cmin0));
    atomicMin(&colminL[p1], __float_as_uint(cmin1));
    __syncthreads();

    if (t < 128) {
        float cv = __uint_as_float(rowminL[t]);
        #pragma unroll
        for (int o = 32; o; o >>= 1) cv += __shfl_xor(cv, o);
        if ((t & 63) == 0) atomicAdd(cov_out, cv);
    }
    if (t < 128) atomicMin(&proto_min[t], colminL[t]);
}

// ---------------- dist body SLOW (no-preconv fallback, verified R5) ---------
__device__ __forceinline__ void dist_body_slow(SmemU& sm, int bid,
                                               const float* __restrict__ emb,
                                               const float* __restrict__ proto,
                                               unsigned* __restrict__ proto_min,
                                               float* __restrict__ cov_out) {
    char*     AsB     = sm.dist.As;
    char*     BsB     = sm.dist.Bs;
    float*    rownL   = sm.dist.rown;
    float*    pnL     = sm.dist.pn;
    unsigned* rowminL = sm.dist.rowmin;
    unsigned* colminL = sm.dist.colmin;

    const int t  = threadIdx.x;
    const int m0 = bid * 64;

    if (t < 64)  { rownL[t] = 0.f; rowminL[t] = 0x7F7F7F7Fu; }
    if (t < 128) { colminL[t] = 0x7F7F7F7Fu; pnL[t] = 0.f; }
    __syncthreads();

    const int ra = t >> 2, qa = t & 3;
    const int pb = t >> 1, hb = t & 1;
    const int raz = ra & 7, pbz = pb & 7;

    const float4* aG  = (const float4*)(emb + (size_t)(m0 + ra) * 512 + qa * 16);
    const float4* bGf = (const float4*)(proto + (size_t)pb * 512 + hb * 32);

    const int lane = t & 63, wv = t >> 6;
    const int wr = wv >> 1, wc = wv & 1;
    const int lo = lane & 31, hi = lane >> 5;
    const int arow = wr * 32 + lo;
    const int arz  = arow & 7;
    const int p0 = wc * 64 + lo, p1 = p0 + 32;
    const int pz = p0 & 7;

    float4 av0 = aG[0], av1 = aG[1], av2 = aG[2], av3 = aG[3];
    float4 bf0 = bGf[0], bf1 = bGf[1], bf2 = bGf[2], bf3 = bGf[3],
           bf4 = bGf[4], bf5 = bGf[5], bf6 = bGf[6], bf7 = bGf[7];

    f32x16 acc0 = {}, acc1 = {};
    char* Aw = AsB + ra * 128;
    char* Bw = BsB + pb * 128;
    const char* Ar  = AsB + arow * 128;
    const char* Br0 = BsB + p0 * 128;
    const char* Br1 = BsB + p1 * 128;

    for (int c = 0; c < 8; ++c) {
        {
            float nx = 0.f;
            nx = fmaf(av0.x, av0.x, nx); nx = fmaf(av0.y, av0.y, nx);
            nx = fmaf(av0.z, av0.z, nx); nx = fmaf(av0.w, av0.w, nx);
            nx = fmaf(av1.x, av1.x, nx); nx = fmaf(av1.y, av1.y, nx);
            nx = fmaf(av1.z, av1.z, nx); nx = fmaf(av1.w, av1.w, nx);
            nx = fmaf(av2.x, av2.x, nx); nx = fmaf(av2.y, av2.y, nx);
            nx = fmaf(av2.z, av2.z, nx); nx = fmaf(av2.w, av2.w, nx);
            nx = fmaf(av3.x, av3.x, nx); nx = fmaf(av3.y, av3.y, nx);
            nx = fmaf(av3.z, av3.z, nx); nx = fmaf(av3.w, av3.w, nx);
            atomicAdd(&rownL[ra], nx);
            u16x8 w0 = { f2b(av0.x), f2b(av0.y), f2b(av0.z), f2b(av0.w),
                         f2b(av1.x), f2b(av1.y), f2b(av1.z), f2b(av1.w) };
            u16x8 w1 = { f2b(av2.x), f2b(av2.y), f2b(av2.z), f2b(av2.w),
                         f2b(av3.x), f2b(av3.y), f2b(av3.z), f2b(av3.w) };
            *(u16x8*)(Aw + (((qa * 2 + 0) ^ raz) << 4)) = w0;
            *(u16x8*)(Aw + (((qa * 2 + 1) ^ raz) << 4)) = w1;

            float pns = 0.f;
            pns = fmaf(bf0.x, bf0.x, pns); pns = fmaf(bf0.y, bf0.y, pns);
            pns = fmaf(bf0.z, bf0.z, pns); pns = fmaf(bf0.w, bf0.w, pns);
            pns = fmaf(bf1.x, bf1.x, pns); pns = fmaf(bf1.y, bf1.y, pns);
            pns = fmaf(bf1.z, bf1.z, pns); pns = fmaf(bf1.w, bf1.w, pns);
            pns = fmaf(bf2.x, bf2.x, pns); pns = fmaf(bf2.y, bf2.y, pns);
            pns = fmaf(bf2.z, bf2.z, pns); pns = fmaf(bf2.w, bf2.w, pns);
            pns = fmaf(bf3.x, bf3.x, pns); pns = fmaf(bf3.y, bf3.y, pns);
            pns = fmaf(bf3.z, bf3.z, pns); pns = fmaf(bf3.w, bf3.w, pns);
            pns = fmaf(bf4.x, bf4.x, pns); pns = fmaf(bf4.y, bf4.y, pns);
            pns = fmaf(bf4.z, bf4.z, pns); pns = fmaf(bf4.w, bf4.w, pns);
            pns = fmaf(bf5.x, bf5.x, pns); pns = fmaf(bf5.y, bf5.y, pns);
            pns = fmaf(bf5.z, bf5.z, pns); pns = fmaf(bf5.w, bf5.w, pns);
            pns = fmaf(bf6.x, bf6.x, pns); pns = fmaf(bf6.y, bf6.y, pns);
            pns = fmaf(bf6.z, bf6.z, pns); pns = fmaf(bf6.w, bf6.w, pns);
            pns = fmaf(bf7.x, bf7.x, pns); pns = fmaf(bf7.y, bf7.y, pns);
            pns = fmaf(bf7.z, bf7.z, pns); pns = fmaf(bf7.w, bf7.w, pns);
            atomicAdd(&pnL[pb], pns);
            u16x8 x0 = { f2b(bf0.x), f2b(bf0.y), f2b(bf0.z), f2b(bf0.w),
                         f2b(bf1.x), f2b(bf1.y), f2b(bf1.z), f2b(bf1.w) };
            u16x8 x1 = { f2b(bf2.x), f2b(bf2.y), f2b(bf2.z), f2b(bf2.w),
                         f2b(bf3.x), f2b(bf3.y), f2b(bf3.z), f2b(bf3.w) };
            u16x8 x2 = { f2b(bf4.x), f2b(bf4.y), f2b(bf4.z), f2b(bf4.w),
                         f2b(bf5.x), f2b(bf5.y), f2b(bf5.z), f2b(bf5.w) };
            u16x8 x3 = { f2b(bf6.x), f2b(bf6.y), f2b(bf6.z), f2b(bf6.w),
                         f2b(bf7.x), f2b(bf7.y), f2b(bf7.z), f2b(bf7.w) };
            *(u16x8*)(Bw + (((hb * 4 + 0) ^ pbz) << 4)) = x0;
            *(u16x8*)(Bw + (((hb * 4 + 1) ^ pbz) << 4)) = x1;
            *(u16x8*)(Bw + (((hb * 4 + 2) ^ pbz) << 4)) = x2;
            *(u16x8*)(Bw + (((hb * 4 + 3) ^ pbz) << 4)) = x3;
        }
        __syncthreads();
        if (c < 7) {
            av0 = aG[(c + 1) * 16 + 0]; av1 = aG[(c + 1) * 16 + 1];
            av2 = aG[(c + 1) * 16 + 2]; av3 = aG[(c + 1) * 16 + 3];
            bf0 = bGf[(c + 1) * 16 + 0]; bf1 = bGf[(c + 1) * 16 + 1];
            bf2 = bGf[(c + 1) * 16 + 2]; bf3 = bGf[(c + 1) * 16 + 3];
            bf4 = bGf[(c + 1) * 16 + 4]; bf5 = bGf[(c + 1) * 16 + 5];
            bf6 = bGf[(c + 1) * 16 + 6]; bf7 = bGf[(c + 1) * 16 + 7];
        }
        #pragma unroll
        for (int s = 0; s < 4; ++s) {
            const int g = (s * 2 + hi);
            bf16x8 af = *(const bf16x8*)(Ar  + ((g ^ arz) << 4));
            bf16x8 b0 = *(const bf16x8*)(Br0 + ((g ^ pz)  << 4));
            bf16x8 b1 = *(const bf16x8*)(Br1 + ((g ^ pz)  << 4));
            acc0 = __builtin_amdgcn_mfma_f32_32x32x16_bf16(af, b0, acc0, 0, 0, 0);
            acc1 = __builtin_amdgcn_mfma_f32_32x32x16_bf16(af, b1, acc1, 0, 0, 0);
        }
        __syncthreads();
    }

    const float pn0 = pnL[p0], pn1 = pnL[p1];
    float cmin0 = 3.0e38f, cmin1 = 3.0e38f;
    #pragma unroll
    for (int r = 0; r < 16; ++r) {
        const int row = wr * 32 + (r & 3) + 8 * (r >> 2) + 4 * hi;
        const float nx = rownL[row];
        float d0 = sqrtf(fmaxf(nx + pn0 - 2.f * acc0[r], FEPS));
        float d1 = sqrtf(fmaxf(nx + pn1 - 2.f * acc1[r], FEPS));
        cmin0 = fminf(cmin0, d0);
        cmin1 = fminf(cmin1, d1);
        atomicMin(&rowminL[row], __float_as_uint(fminf(d0, d1)));
    }
    atomicMin(&colminL[p0], __float_as_uint(cmin0));
    atomicMin(&colminL[p1], __float_as_uint(cmin1));
    __syncthreads();

    if (t < 64) {
        float cv = __uint_as_float(rowminL[t]);
        #pragma unroll
        for (int o = 32; o; o >>= 1) cv += __shfl_xor(cv, o);
        if (t == 0) atomicAdd(cov_out, cv);
    }
    if (t < 128) atomicMin(&proto_min[t], colminL[t]);
}

// ---------------- mse body: contiguous chunk, 8-deep MLP, nt loads ----------
__device__ __forceinline__ void mse_body(SmemU& sm, int mb,
                                         const float4* __restrict__ r,
                                         const float4* __restrict__ d,
                                         float* __restrict__ out, int n4) {
    const int t  = threadIdx.x;
    const int CH = (n4 + NB_MSE - 1) / NB_MSE;
    const int base = mb * CH;
    const int L = (base + CH <= n4) ? CH : (n4 - base);
    const f32x4* rb = (const f32x4*)(r + base);
    const f32x4* db = (const f32x4*)(d + base);
    float acc0 = 0.f, acc1 = 0.f, acc2 = 0.f, acc3 = 0.f;
    int k = t;
    for (; k + 7 * 256 < L; k += 8 * 256) {
        f32x4 a0 = __builtin_nontemporal_load(&rb[k + 0 * 256]);
        f32x4 a1 = __builtin_nontemporal_load(&rb[k + 1 * 256]);
        f32x4 a2 = __builtin_nontemporal_load(&rb[k + 2 * 256]);
        f32x4 a3 = __builtin_nontemporal_load(&rb[k + 3 * 256]);
        f32x4 a4 = __builtin_nontemporal_load(&rb[k + 4 * 256]);
        f32x4 a5 = __builtin_nontemporal_load(&rb[k + 5 * 256]);
        f32x4 a6 = __builtin_nontemporal_load(&rb[k + 6 * 256]);
        f32x4 a7 = __builtin_nontemporal_load(&rb[k + 7 * 256]);
        f32x4 b0 = __builtin_nontemporal_load(&db[k + 0 * 256]);
        f32x4 b1 = __builtin_nontemporal_load(&db[k + 1 * 256]);
        f32x4 b2 = __builtin_nontemporal_load(&db[k + 2 * 256]);
        f32x4 b3 = __builtin_nontemporal_load(&db[k + 3 * 256]);
        f32x4 b4 = __builtin_nontemporal_load(&db[k + 4 * 256]);
        f32x4 b5 = __builtin_nontemporal_load(&db[k + 5 * 256]);
        f32x4 b6 = __builtin_nontemporal_load(&db[k + 6 * 256]);
        f32x4 b7 = __builtin_nontemporal_load(&db[k + 7 * 256]);
        f32x4 e;
        e = a0 - b0; acc0 = fmaf(e.x, e.x, acc0); acc1 = fmaf(e.y, e.y, acc1);
                     acc2 = fmaf(e.z, e.z, acc2); acc3 = fmaf(e.w, e.w, acc3);
        e = a1 - b1; acc0 = fmaf(e.x, e.x, acc0); acc1 = fmaf(e.y, e.y, acc1);
                     acc2 = fmaf(e.z, e.z, acc2); acc3 = fmaf(e.w, e.w, acc3);
        e = a2 - b2; acc0 = fmaf(e.x, e.x, acc0); acc1 = fmaf(e.y, e.y, acc1);
                     acc2 = fmaf(e.z, e.z, acc2); acc3 = fmaf(e.w, e.w, acc3);
        e = a3 - b3; acc0 = fmaf(e.x, e.x, acc0); acc1 = fmaf(e.y, e.y, acc1);
                     acc2 = fmaf(e.z, e.z, acc2); acc3 = fmaf(e.w, e.w, acc3);
        e = a4 - b4; acc0 = fmaf(e.x, e.x, acc0); acc1 = fmaf(e.y, e.y, acc1);
                     acc2 = fmaf(e.z, e.z, acc2); acc3 = fmaf(e.w, e.w, acc3);
        e = a5 - b5; acc0 = fmaf(e.x, e.x, acc0); acc1 = fmaf(e.y, e.y, acc1);
                     acc2 = fmaf(e.z, e.z, acc2); acc3 = fmaf(e.w, e.w, acc3);
        e = a6 - b6; acc0 = fmaf(e.x, e.x, acc0); acc1 = fmaf(e.y, e.y, acc1);
                     acc2 = fmaf(e.z, e.z, acc2); acc3 = fmaf(e.w, e.w, acc3);
        e = a7 - b7; acc0 = fmaf(e.x, e.x, acc0); acc1 = fmaf(e.y, e.y, acc1);
                     acc2 = fmaf(e.z, e.z, acc2); acc3 = fmaf(e.w, e.w, acc3);
    }
    for (; k < L; k += 256) {
        f32x4 a = __builtin_nontemporal_load(&rb[k]);
        f32x4 b = __builtin_nontemporal_load(&db[k]);
        f32x4 e = a - b;
        acc0 = fmaf(e.x, e.x, acc0); acc1 = fmaf(e.y, e.y, acc1);
        acc2 = fmaf(e.z, e.z, acc2); acc3 = fmaf(e.w, e.w, acc3);
    }
    float acc = (acc0 + acc1) + (acc2 + acc3);
    #pragma unroll
    for (int o = 32; o; o >>= 1) acc += __shfl_xor(acc, o);
    int lane = t & 63, w = t >> 6;
    if (lane == 0) sm.red.sred[w] = acc;
    __syncthreads();
    if (t == 0) atomicAdd(out, sm.red.sred[0] + sm.red.sred[1]
                             + sm.red.sred[2] + sm.red.sred[3]);
}

// ---------------- ce body ---------------------------------------------------
__device__ __forceinline__ void ce_body(SmemU& sm, int cb,
                                        const float* __restrict__ pred,
                                        const int* __restrict__ lab,
                                        float* __restrict__ ce_out,
                                        int B, int C) {
    const int rows_per_wave = B / (NB_CE * 4);
    int lane = threadIdx.x & 63;
    int w    = threadIdx.x >> 6;
    int wid  = cb * 4 + w;
    float acc = 0.f;
    for (int i = 0; i < rows_per_wave; ++i) {
        int row = wid * rows_per_wave + i;
        const float* p = pred + (size_t)row * C;
        float v1 = (lane < C)      ? p[lane]      : -3.0e38f;
        float v2 = (lane + 64 < C) ? p[lane + 64] : -3.0e38f;
        float m = fmaxf(v1, v2);
        #pragma unroll
        for (int o = 32; o; o >>= 1) m = fmaxf(m, __shfl_xor(m, o));
        float s = ((lane < C) ? __expf(v1 - m) : 0.f)
                + ((lane + 64 < C) ? __expf(v2 - m) : 0.f);
        #pragma unroll
        for (int o = 32; o; o >>= 1) s += __shfl_xor(s, o);
        float lv = p[lab[row]];
        acc += m + __logf(s) - lv;
    }
    if (lane == 0) sm.red.sred[w] = acc;
    __syncthreads();
    if (threadIdx.x == 0) atomicAdd(ce_out, sm.red.sred[0] + sm.red.sred[1]
                                          + sm.red.sred[2] + sm.red.sred[3]);
}

// ---------------- div body --------------------------------------------------
__device__ __forceinline__ void div_body(SmemU& sm, int p,
                                         const float* __restrict__ proto,
                                         float* __restrict__ div_out, int dd) {
    int q = threadIdx.x;
    bool act = q < 128;
    if (act) for (int k = q; k < dd; k += 128) sm.div.pp[k] = proto[(size_t)p * dd + k];
    __syncthreads();
    float dot = 0.f, qq = 0.f;
    if (act) {
        const float4* pq4 = (const float4*)(proto + (size_t)q * dd);
        const float4* pp4 = (const float4*)sm.div.pp;
        for (int k4 = 0; k4 < dd / 4; ++k4) {
            float4 v = pq4[k4];
            float4 u = pp4[k4];
            dot = fmaf(u.x, v.x, dot); dot = fmaf(u.y, v.y, dot);
            dot = fmaf(u.z, v.z, dot); dot = fmaf(u.w, v.w, dot);
            qq  = fmaf(v.x, v.x, qq);  qq  = fmaf(v.y, v.y, qq);
            qq  = fmaf(v.z, v.z, qq);  qq  = fmaf(v.w, v.w, qq);
        }
        if (q == p) sm.div.spp = qq;
    }
    __syncthreads();
    float h2 = 0.f;
    if (act && q > p) {
        float sq = sm.div.spp + qq - 2.f * dot;
        float dist = sqrtf(fmaxf(sq, FEPS));
        float h = fmaxf(0.f, DMIN - dist);
        h2 = h * h;
    }
    #pragma unroll
    for (int o = 32; o; o >>= 1) h2 += __shfl_xor(h2, o);
    if ((q & 63) == 0) sm.div.sred[q >> 6] = h2;
    __syncthreads();
    if (q == 0) atomicAdd(div_out, sm.div.sred[0] + sm.div.sred[1]
                                 + sm.div.sred[2] + sm.div.sred[3]);
}

// ---------------- fused kernel (+ last-block final combine) -----------------
template<bool PRECONV>
__global__ __launch_bounds__(256) void fused_kernel(
        const float* __restrict__ pred, const int* __restrict__ lab,
        const float4* __restrict__ recon4, const float4* __restrict__ data4,
        const float* __restrict__ emb, const float* __restrict__ proto,
        const ushort_t* __restrict__ pB, const float* __restrict__ pnormG,
        float* __restrict__ ws, unsigned* __restrict__ proto_min,
        unsigned* __restrict__ donec, float* __restrict__ out,
        int B, int C, int n4, int dd) {
    __shared__ __attribute__((aligned(16))) SmemU sm;
    __shared__ unsigned last_flag;
    __shared__ float fin[4];
    int bid = blockIdx.x;
    if (bid < NB_DIST) {
        if constexpr (PRECONV) {
            dist_body_fast(sm, bid, emb, pB, pnormG, proto_min, ws + 3);
        } else {
            dist_body_slow(sm, bid * 2, emb, proto, proto_min, ws + 3);
            __syncthreads();
            dist_body_slow(sm, bid * 2 + 1, emb, proto, proto_min, ws + 3);
        }
    } else if (bid < NB_DIST + NB_MSE) {
        mse_body(sm, bid - NB_DIST, recon4, data4, ws + 1, n4);
    } else if (bid < NB_DIST + NB_MSE + NB_CE) {
        ce_body(sm, bid - NB_DIST - NB_MSE, pred, lab, ws + 0, B, C);
    } else {
        div_body(sm, bid - NB_DIST - NB_MSE - NB_CE, proto, ws + 2, dd);
    }

    // ---- last block computes the final combine (no extra launch) ----
    __syncthreads();                   // drains this block's vmem (incl atomics)
    if (threadIdx.x == 0) {
        __threadfence();               // publish before counting
        unsigned prev = atomicAdd(donec, 1u);
        last_flag = (prev == (unsigned)(GRID_TOTAL - 1)) ? 1u : 0u;
    }
    __syncthreads();
    if (last_flag) {
        __threadfence();               // acquire: others' atomics visible
        int t = threadIdx.x;
        float sim = 0.f;
        if (t < 128) sim = __uint_as_float(proto_min[t]);
        #pragma unroll
        for (int o = 32; o; o >>= 1) sim += __shfl_xor(sim, o);
        if ((t & 63) == 0) fin[t >> 6] = sim;
        __syncthreads();
        if (t == 0) {
            float simv = fin[0] + fin[1];
            float ce   = ws[0] / (float)B;
            float mse  = ws[1] / ((float)B * 1024.f);
            out[0] = ce + 0.05f * mse + 0.05f * ws[2]
                   + 0.05f * (simv / 128.f) + 0.05f * (ws[3] / (float)B);
        }
    }
}

extern "C" void kernel_launch(void* const* d_in, const int* in_sizes, int n_in,
                              void* d_out, int out_size, void* d_ws, size_t ws_size,
                              hipStream_t stream) {
    const float* pred  = (const float*)d_in[0];
    const float* recon = (const float*)d_in[1];
    const float* data  = (const float*)d_in[2];
    const float* emb   = (const float*)d_in[3];
    const float* proto = (const float*)d_in[4];
    const int*   lab   = (const int*)d_in[5];
    float* out = (float*)d_out;

    int B  = in_sizes[5];            // 32768
    int C  = in_sizes[0] / B;        // 100
    int D  = in_sizes[1] / B;        // 1024
    int dd = in_sizes[3] / B;        // 512
    int P  = in_sizes[4] / dd;       // 128

    float* ws = (float*)d_ws;
    // ws layout: [0]=ce [1]=mse [2]=div [3]=cov ; [4..131]=proto_min bits ;
    //            [132..259]=pnorm ; [260]=done counter ;
    //            byte 1280.. : pB bf16 [128][512]
    unsigned* proto_min = (unsigned*)(ws + 4);
    float*    pnorm     = ws + 132;
    unsigned* donec     = (unsigned*)(ws + 260);
    ushort_t* pB        = (ushort_t*)((char*)d_ws + 1280);
    bool preconv = ws_size >= (size_t)(1280 + 128 * 512 * 2);

    int n4 = (B * D) / 4;
    if (preconv) {
        conv_kernel<<<128, 128, 0, stream>>>(proto, pB, pnorm, ws, proto_min, donec);
        fused_kernel<true><<<GRID_TOTAL, 256, 0, stream>>>(
            pred, lab, (const float4*)recon, (const float4*)data, emb, proto,
            pB, pnorm, ws, proto_min, donec, out, B, C, n4, dd);
    } else {
        hipMemsetAsync(ws, 0, 4 * sizeof(float), stream);
        hipMemsetAsync(ws + 4, 0x7F, P * sizeof(unsigned), stream);
        hipMemsetAsync(ws + 260, 0, sizeof(unsigned), stream);
        fused_kernel<false><<<GRID_TOTAL, 256, 0, stream>>>(
            pred, lab, (const float4*)recon, (const float4*)data, emb, proto,
            nullptr, nullptr, ws, proto_min, donec, out, B, C, n4, dd);
    }
}

// Round 13
// 98.143 us; speedup vs baseline: 1.4536x; 1.4536x over previous
//
#include <hip/hip_runtime.h>
#include <hip/hip_bf16.h>

// ---------------------------------------------------------------------------
// total = CE + 0.05*MSE + 0.05*div + 0.05*sim + 0.05*cov
// Round 13: REVERT to R11 champion (98.9 µs). R12's last-block fold cost
// 1664 device-scope threadfences (L2 writeback across 8 non-coherent XCDs)
// — -44 µs. Champion: 2-tile dist (shared B, cross-chunk vmcnt(12)),
// NT 8-deep MSE, separate final_kernel.
// ---------------------------------------------------------------------------

constexpr float FEPS = 1e-12f;
constexpr float DMIN = 1.0f;

#define NB_DIST 256
#define NB_MSE  1024
#define NB_CE   256
#define NB_DIV  128

typedef unsigned short ushort_t;
typedef __attribute__((ext_vector_type(8))) short bf16x8;
typedef __attribute__((ext_vector_type(8))) unsigned short u16x8;
typedef __attribute__((ext_vector_type(4))) unsigned short u16x4;
typedef __attribute__((ext_vector_type(16))) float f32x16;
typedef __attribute__((ext_vector_type(4))) float f32x4;

typedef __attribute__((address_space(1))) const void gvoid_t;
typedef __attribute__((address_space(3))) void lvoid_t;

__device__ __forceinline__ unsigned short f2b(float f) {
    unsigned u = __float_as_uint(f);
    u += 0x7FFFu + ((u >> 16) & 1u);   // RNE to bf16
    return (unsigned short)(u >> 16);
}

union SmemU {
    struct {
        char     As[2 * 8192];     // 2 tiles x 64 rows x 128B bf16, swizzled
        char     Bs[2 * 16384];    // dbuf: 128 protos x 128B bf16 (swz via src)
        float    rown[128];        // [tile*64 + row]
        float    pn[128];
        unsigned rowmin[128];
        unsigned colmin[128];
    } dist;                        // 51200 B -> 3 blocks/CU
    struct { float pp[512]; float spp; float sred[4]; } div;
    struct { float sred[4]; } red;
};

// -------- proto fp32 -> bf16 (linear [p][k]) + norms + accumulator init -----
__global__ __launch_bounds__(128) void conv_kernel(const float* __restrict__ proto,
                                                   ushort_t* __restrict__ pB,
                                                   float* __restrict__ pnorm,
                                                   float* __restrict__ ws,
                                                   unsigned* __restrict__ proto_min) {
    int p = blockIdx.x, q = threadIdx.x;
    if (q == 0) proto_min[p] = 0x7F7F7F7Fu;
    if (p == 0 && q < 4) ws[q] = 0.f;
    float4 v = ((const float4*)(proto + (size_t)p * 512))[q];
    u16x4 o = { f2b(v.x), f2b(v.y), f2b(v.z), f2b(v.w) };
    *(u16x4*)(pB + (size_t)p * 512 + q * 4) = o;
    float s = v.x * v.x + v.y * v.y + v.z * v.z + v.w * v.w;
    #pragma unroll
    for (int off = 32; off; off >>= 1) s += __shfl_xor(s, off);
    __shared__ float sr[2];
    if ((q & 63) == 0) sr[q >> 6] = s;
    __syncthreads();
    if (q == 0) pnorm[p] = sr[0] + sr[1];
}

// ---------------- dist body FAST: 2-tile interleaved, counted vmcnt ---------
__device__ __forceinline__ void dist_body_fast(SmemU& sm, int bid,
                                               const float* __restrict__ emb,
                                               const ushort_t* __restrict__ pB,
                                               const float* __restrict__ pnormG,
                                               unsigned* __restrict__ proto_min,
                                               float* __restrict__ cov_out) {
    char*     AsB     = sm.dist.As;
    char*     BsB     = sm.dist.Bs;
    float*    rownL   = sm.dist.rown;
    float*    pnL     = sm.dist.pn;
    unsigned* rowminL = sm.dist.rowmin;
    unsigned* colminL = sm.dist.colmin;

    const int t  = threadIdx.x;
    const int m0 = bid * 128;      // this block covers rows m0 .. m0+127

    if (t < 128) {
        rownL[t] = 0.f; rowminL[t] = 0x7F7F7F7Fu;
        colminL[t] = 0x7F7F7F7Fu; pnL[t] = pnormG[t];
    }

    // ---- A coalesced map (tile-local): flat=i*256+t; row=flat>>4; colq=flat&15
    int aidx[4], rowi[4], swzi[4];
    const float4* embF4 = (const float4*)emb;
    #pragma unroll
    for (int i = 0; i < 4; ++i) {
        int flat = i * 256 + t;
        int row = flat >> 4, colq = flat & 15;
        rowi[i] = row;
        aidx[i] = (m0 + row) * 128 + colq;      // tile1 adds 8192 (64 rows)
        swzi[i] = row * 128 + ((((colq >> 1) ^ (row & 7)) << 4) | ((colq & 1) << 3));
    }

    // ---- B gl_lds map: f=i*256+t; pr=f>>3; gb=f&7 (linear dest, swz source)
    const ushort_t* bsrcp[4];
    char* bdstW[4];
    #pragma unroll
    for (int i = 0; i < 4; ++i) {
        int f = i * 256 + t;
        int pr = f >> 3, gb = f & 7;
        bsrcp[i] = pB + pr * 512 + ((gb ^ (pr & 7)) << 3);
        bdstW[i] = BsB + (size_t)(i * 256 + (t & ~63)) * 16;   // wave-uniform
    }

    // ---- fragment geometry (per tile)
    const int lane = t & 63, wv = t >> 6;
    const int wr = wv >> 1, wc = wv & 1;
    const int lo = lane & 31, hi = lane >> 5;
    const int arow = wr * 32 + lo;
    const int arz  = arow & 7;
    const int p0 = wc * 64 + lo, p1 = p0 + 32;
    const int pz = p0 & 7;
    const char* Ar0 = AsB + arow * 128;
    const char* Ar1 = AsB + 8192 + arow * 128;
    const char* Br0 = BsB + p0 * 128;
    const char* Br1 = BsB + p1 * 128;

    // prologue: B(0) -> Bs buf0 ; A(0) both tiles -> regs
    __builtin_amdgcn_global_load_lds((gvoid_t*)(bsrcp[0]), (lvoid_t*)bdstW[0], 16, 0, 0);
    __builtin_amdgcn_global_load_lds((gvoid_t*)(bsrcp[1]), (lvoid_t*)bdstW[1], 16, 0, 0);
    __builtin_amdgcn_global_load_lds((gvoid_t*)(bsrcp[2]), (lvoid_t*)bdstW[2], 16, 0, 0);
    __builtin_amdgcn_global_load_lds((gvoid_t*)(bsrcp[3]), (lvoid_t*)bdstW[3], 16, 0, 0);
    float4 a00 = embF4[aidx[0]],        a01 = embF4[aidx[1]],
           a02 = embF4[aidx[2]],        a03 = embF4[aidx[3]];
    float4 a10 = embF4[aidx[0] + 8192], a11 = embF4[aidx[1] + 8192],
           a12 = embF4[aidx[2] + 8192], a13 = embF4[aidx[3] + 8192];
    float rn00 = 0.f, rn01 = 0.f, rn02 = 0.f, rn03 = 0.f;
    float rn10 = 0.f, rn11 = 0.f, rn12 = 0.f, rn13 = 0.f;
    f32x16 acc00 = {}, acc01 = {}, acc10 = {}, acc11 = {};
    asm volatile("s_waitcnt lgkmcnt(0)" ::: "memory");   // init visible
    __builtin_amdgcn_s_barrier();
    __builtin_amdgcn_sched_barrier(0);

// Per chunk: [issue B(c+1)] [consume A(c): norms+f2b+LDS write, both tiles]
// [reload A(c+1) into same regs] [vmcnt(12): only B(c+1)+A(c+1) newer =>
// B(c) landed; compiler auto-waits A deps] [barrier] [16 MFMA] [barrier].
#define FNORM(v, rn) rn = fmaf(v.x, v.x, rn); rn = fmaf(v.y, v.y, rn);         \
                     rn = fmaf(v.z, v.z, rn); rn = fmaf(v.w, v.w, rn);
#define AWRITE(v, base, i) { u16x4 u = { f2b(v.x), f2b(v.y), f2b(v.z), f2b(v.w) }; \
                             *(u16x4*)((base) + swzi[i]) = u; }
#define DIST_CHUNK(c, WAITN)                                                   \
    {                                                                          \
        if ((c) < 7) {                                                         \
            const int kc1 = ((c) + 1) * 64;                                    \
            const int bo1 = (((c) + 1) & 1) * 16384;                           \
            __builtin_amdgcn_global_load_lds((gvoid_t*)(bsrcp[0] + kc1),       \
                (lvoid_t*)(bdstW[0] + bo1), 16, 0, 0);                         \
            __builtin_amdgcn_global_load_lds((gvoid_t*)(bsrcp[1] + kc1),       \
                (lvoid_t*)(bdstW[1] + bo1), 16, 0, 0);                         \
            __builtin_amdgcn_global_load_lds((gvoid_t*)(bsrcp[2] + kc1),       \
                (lvoid_t*)(bdstW[2] + bo1), 16, 0, 0);                         \
            __builtin_amdgcn_global_load_lds((gvoid_t*)(bsrcp[3] + kc1),       \
                (lvoid_t*)(bdstW[3] + bo1), 16, 0, 0);                         \
        }                                                                      \
        __builtin_amdgcn_sched_barrier(0);                                     \
        FNORM(a00, rn00) FNORM(a01, rn01) FNORM(a02, rn02) FNORM(a03, rn03)    \
        FNORM(a10, rn10) FNORM(a11, rn11) FNORM(a12, rn12) FNORM(a13, rn13)    \
        AWRITE(a00, AsB, 0) AWRITE(a01, AsB, 1)                                \
        AWRITE(a02, AsB, 2) AWRITE(a03, AsB, 3)                                \
        AWRITE(a10, AsB + 8192, 0) AWRITE(a11, AsB + 8192, 1)                  \
        AWRITE(a12, AsB + 8192, 2) AWRITE(a13, AsB + 8192, 3)                  \
        if ((c) < 7) {                                                         \
            const int kn = ((c) + 1) * 16;                                     \
            a00 = embF4[aidx[0] + kn];        a01 = embF4[aidx[1] + kn];       \
            a02 = embF4[aidx[2] + kn];        a03 = embF4[aidx[3] + kn];       \
            a10 = embF4[aidx[0] + 8192 + kn]; a11 = embF4[aidx[1] + 8192 + kn];\
            a12 = embF4[aidx[2] + 8192 + kn]; a13 = embF4[aidx[3] + 8192 + kn];\
        }                                                                      \
        __builtin_amdgcn_sched_barrier(0);                                     \
        asm volatile("s_waitcnt vmcnt(" #WAITN ")" ::: "memory");              \
        asm volatile("s_waitcnt lgkmcnt(0)" ::: "memory");                     \
        __builtin_amdgcn_s_barrier();                                          \
        __builtin_amdgcn_sched_barrier(0);                                     \
        {                                                                      \
            const int bo = ((c) & 1) * 16384;                                  \
            _Pragma("unroll")                                                  \
            for (int s = 0; s < 4; ++s) {                                      \
                const int g = (s * 2 + hi);                                    \
                bf16x8 af0 = *(const bf16x8*)(Ar0 + ((g ^ arz) << 4));         \
                bf16x8 af1 = *(const bf16x8*)(Ar1 + ((g ^ arz) << 4));         \
                bf16x8 b0  = *(const bf16x8*)(Br0 + bo + ((g ^ pz) << 4));     \
                bf16x8 b1  = *(const bf16x8*)(Br1 + bo + ((g ^ pz) << 4));     \
                acc00 = __builtin_amdgcn_mfma_f32_32x32x16_bf16(af0, b0, acc00, 0,0,0); \
                acc01 = __builtin_amdgcn_mfma_f32_32x32x16_bf16(af0, b1, acc01, 0,0,0); \
                acc10 = __builtin_amdgcn_mfma_f32_32x32x16_bf16(af1, b0, acc10, 0,0,0); \
                acc11 = __builtin_amdgcn_mfma_f32_32x32x16_bf16(af1, b1, acc11, 0,0,0); \
            }                                                                  \
        }                                                                      \
        asm volatile("s_waitcnt lgkmcnt(0)" ::: "memory");                     \
        __builtin_amdgcn_s_barrier();                                          \
        __builtin_amdgcn_sched_barrier(0);                                     \
    }

    DIST_CHUNK(0, 12)
    DIST_CHUNK(1, 12)
    DIST_CHUNK(2, 12)
    DIST_CHUNK(3, 12)
    DIST_CHUNK(4, 12)
    DIST_CHUNK(5, 12)
    DIST_CHUNK(6, 12)
    DIST_CHUNK(7, 0)
#undef DIST_CHUNK
#undef AWRITE
#undef FNORM

    atomicAdd(&rownL[rowi[0]], rn00);
    atomicAdd(&rownL[rowi[1]], rn01);
    atomicAdd(&rownL[rowi[2]], rn02);
    atomicAdd(&rownL[rowi[3]], rn03);
    atomicAdd(&rownL[64 + rowi[0]], rn10);
    atomicAdd(&rownL[64 + rowi[1]], rn11);
    atomicAdd(&rownL[64 + rowi[2]], rn12);
    atomicAdd(&rownL[64 + rowi[3]], rn13);
    __syncthreads();

    // epilogue (C/D: col=lane&31, row=(r&3)+8*(r>>2)+4*hi)
    const float pn0 = pnL[p0], pn1 = pnL[p1];
    float cmin0 = 3.0e38f, cmin1 = 3.0e38f;
    #pragma unroll
    for (int r = 0; r < 16; ++r) {
        const int row = wr * 32 + (r & 3) + 8 * (r >> 2) + 4 * hi;
        const float nx0 = rownL[row];
        const float nx1 = rownL[64 + row];
        float d00 = sqrtf(fmaxf(nx0 + pn0 - 2.f * acc00[r], FEPS));
        float d01 = sqrtf(fmaxf(nx0 + pn1 - 2.f * acc01[r], FEPS));
        float d10 = sqrtf(fmaxf(nx1 + pn0 - 2.f * acc10[r], FEPS));
        float d11 = sqrtf(fmaxf(nx1 + pn1 - 2.f * acc11[r], FEPS));
        cmin0 = fminf(cmin0, fminf(d00, d10));
        cmin1 = fminf(cmin1, fminf(d01, d11));
        atomicMin(&rowminL[row],      __float_as_uint(fminf(d00, d01)));
        atomicMin(&rowminL[64 + row], __float_as_uint(fminf(d10, d11)));
    }
    atomicMin(&colminL[p0], __float_as_uint(cmin0));
    atomicMin(&colminL[p1], __float_as_uint(cmin1));
    __syncthreads();

    if (t < 128) {
        float cv = __uint_as_float(rowminL[t]);
        #pragma unroll
        for (int o = 32; o; o >>= 1) cv += __shfl_xor(cv, o);
        if ((t & 63) == 0) atomicAdd(cov_out, cv);
    }
    if (t < 128) atomicMin(&proto_min[t], colminL[t]);
}

// ---------------- dist body SLOW (no-preconv fallback, verified R5) ---------
__device__ __forceinline__ void dist_body_slow(SmemU& sm, int bid,
                                               const float* __restrict__ emb,
                                               const float* __restrict__ proto,
                                               unsigned* __restrict__ proto_min,
                                               float* __restrict__ cov_out) {
    char*     AsB     = sm.dist.As;
    char*     BsB     = sm.dist.Bs;
    float*    rownL   = sm.dist.rown;
    float*    pnL     = sm.dist.pn;
    unsigned* rowminL = sm.dist.rowmin;
    unsigned* colminL = sm.dist.colmin;

    const int t  = threadIdx.x;
    const int m0 = bid * 64;

    if (t < 64)  { rownL[t] = 0.f; rowminL[t] = 0x7F7F7F7Fu; }
    if (t < 128) { colminL[t] = 0x7F7F7F7Fu; pnL[t] = 0.f; }
    __syncthreads();

    const int ra = t >> 2, qa = t & 3;
    const int pb = t >> 1, hb = t & 1;
    const int raz = ra & 7, pbz = pb & 7;

    const float4* aG  = (const float4*)(emb + (size_t)(m0 + ra) * 512 + qa * 16);
    const float4* bGf = (const float4*)(proto + (size_t)pb * 512 + hb * 32);

    const int lane = t & 63, wv = t >> 6;
    const int wr = wv >> 1, wc = wv & 1;
    const int lo = lane & 31, hi = lane >> 5;
    const int arow = wr * 32 + lo;
    const int arz  = arow & 7;
    const int p0 = wc * 64 + lo, p1 = p0 + 32;
    const int pz = p0 & 7;

    float4 av0 = aG[0], av1 = aG[1], av2 = aG[2], av3 = aG[3];
    float4 bf0 = bGf[0], bf1 = bGf[1], bf2 = bGf[2], bf3 = bGf[3],
           bf4 = bGf[4], bf5 = bGf[5], bf6 = bGf[6], bf7 = bGf[7];

    f32x16 acc0 = {}, acc1 = {};
    char* Aw = AsB + ra * 128;
    char* Bw = BsB + pb * 128;
    const char* Ar  = AsB + arow * 128;
    const char* Br0 = BsB + p0 * 128;
    const char* Br1 = BsB + p1 * 128;

    for (int c = 0; c < 8; ++c) {
        {
            float nx = 0.f;
            nx = fmaf(av0.x, av0.x, nx); nx = fmaf(av0.y, av0.y, nx);
            nx = fmaf(av0.z, av0.z, nx); nx = fmaf(av0.w, av0.w, nx);
            nx = fmaf(av1.x, av1.x, nx); nx = fmaf(av1.y, av1.y, nx);
            nx = fmaf(av1.z, av1.z, nx); nx = fmaf(av1.w, av1.w, nx);
            nx = fmaf(av2.x, av2.x, nx); nx = fmaf(av2.y, av2.y, nx);
            nx = fmaf(av2.z, av2.z, nx); nx = fmaf(av2.w, av2.w, nx);
            nx = fmaf(av3.x, av3.x, nx); nx = fmaf(av3.y, av3.y, nx);
            nx = fmaf(av3.z, av3.z, nx); nx = fmaf(av3.w, av3.w, nx);
            atomicAdd(&rownL[ra], nx);
            u16x8 w0 = { f2b(av0.x), f2b(av0.y), f2b(av0.z), f2b(av0.w),
                         f2b(av1.x), f2b(av1.y), f2b(av1.z), f2b(av1.w) };
            u16x8 w1 = { f2b(av2.x), f2b(av2.y), f2b(av2.z), f2b(av2.w),
                         f2b(av3.x), f2b(av3.y), f2b(av3.z), f2b(av3.w) };
            *(u16x8*)(Aw + (((qa * 2 + 0) ^ raz) << 4)) = w0;
            *(u16x8*)(Aw + (((qa * 2 + 1) ^ raz) << 4)) = w1;

            float pns = 0.f;
            pns = fmaf(bf0.x, bf0.x, pns); pns = fmaf(bf0.y, bf0.y, pns);
            pns = fmaf(bf0.z, bf0.z, pns); pns = fmaf(bf0.w, bf0.w, pns);
            pns = fmaf(bf1.x, bf1.x, pns); pns = fmaf(bf1.y, bf1.y, pns);
            pns = fmaf(bf1.z, bf1.z, pns); pns = fmaf(bf1.w, bf1.w, pns);
            pns = fmaf(bf2.x, bf2.x, pns); pns = fmaf(bf2.y, bf2.y, pns);
            pns = fmaf(bf2.z, bf2.z, pns); pns = fmaf(bf2.w, bf2.w, pns);
            pns = fmaf(bf3.x, bf3.x, pns); pns = fmaf(bf3.y, bf3.y, pns);
            pns = fmaf(bf3.z, bf3.z, pns); pns = fmaf(bf3.w, bf3.w, pns);
            pns = fmaf(bf4.x, bf4.x, pns); pns = fmaf(bf4.y, bf4.y, pns);
            pns = fmaf(bf4.z, bf4.z, pns); pns = fmaf(bf4.w, bf4.w, pns);
            pns = fmaf(bf5.x, bf5.x, pns); pns = fmaf(bf5.y, bf5.y, pns);
            pns = fmaf(bf5.z, bf5.z, pns); pns = fmaf(bf5.w, bf5.w, pns);
            pns = fmaf(bf6.x, bf6.x, pns); pns = fmaf(bf6.y, bf6.y, pns);
            pns = fmaf(bf6.z, bf6.z, pns); pns = fmaf(bf6.w, bf6.w, pns);
            pns = fmaf(bf7.x, bf7.x, pns); pns = fmaf(bf7.y, bf7.y, pns);
            pns = fmaf(bf7.z, bf7.z, pns); pns = fmaf(bf7.w, bf7.w, pns);
            atomicAdd(&pnL[pb], pns);
            u16x8 x0 = { f2b(bf0.x), f2b(bf0.y), f2b(bf0.z), f2b(bf0.w),
                         f2b(bf1.x), f2b(bf1.y), f2b(bf1.z), f2b(bf1.w) };
            u16x8 x1 = { f2b(bf2.x), f2b(bf2.y), f2b(bf2.z), f2b(bf2.w),
                         f2b(bf3.x), f2b(bf3.y), f2b(bf3.z), f2b(bf3.w) };
            u16x8 x2 = { f2b(bf4.x), f2b(bf4.y), f2b(bf4.z), f2b(bf4.w),
                         f2b(bf5.x), f2b(bf5.y), f2b(bf5.z), f2b(bf5.w) };
            u16x8 x3 = { f2b(bf6.x), f2b(bf6.y), f2b(bf6.z), f2b(bf6.w),
                         f2b(bf7.x), f2b(bf7.y), f2b(bf7.z), f2b(bf7.w) };
            *(u16x8*)(Bw + (((hb * 4 + 0) ^ pbz) << 4)) = x0;
            *(u16x8*)(Bw + (((hb * 4 + 1) ^ pbz) << 4)) = x1;
            *(u16x8*)(Bw + (((hb * 4 + 2) ^ pbz) << 4)) = x2;
            *(u16x8*)(Bw + (((hb * 4 + 3) ^ pbz) << 4)) = x3;
        }
        __syncthreads();
        if (c < 7) {
            av0 = aG[(c + 1) * 16 + 0]; av1 = aG[(c + 1) * 16 + 1];
            av2 = aG[(c + 1) * 16 + 2]; av3 = aG[(c + 1) * 16 + 3];
            bf0 = bGf[(c + 1) * 16 + 0]; bf1 = bGf[(c + 1) * 16 + 1];
            bf2 = bGf[(c + 1) * 16 + 2]; bf3 = bGf[(c + 1) * 16 + 3];
            bf4 = bGf[(c + 1) * 16 + 4]; bf5 = bGf[(c + 1) * 16 + 5];
            bf6 = bGf[(c + 1) * 16 + 6]; bf7 = bGf[(c + 1) * 16 + 7];
        }
        #pragma unroll
        for (int s = 0; s < 4; ++s) {
            const int g = (s * 2 + hi);
            bf16x8 af = *(const bf16x8*)(Ar  + ((g ^ arz) << 4));
            bf16x8 b0 = *(const bf16x8*)(Br0 + ((g ^ pz)  << 4));
            bf16x8 b1 = *(const bf16x8*)(Br1 + ((g ^ pz)  << 4));
            acc0 = __builtin_amdgcn_mfma_f32_32x32x16_bf16(af, b0, acc0, 0, 0, 0);
            acc1 = __builtin_amdgcn_mfma_f32_32x32x16_bf16(af, b1, acc1, 0, 0, 0);
        }
        __syncthreads();
    }

    const float pn0 = pnL[p0], pn1 = pnL[p1];
    float cmin0 = 3.0e38f, cmin1 = 3.0e38f;
    #pragma unroll
    for (int r = 0; r < 16; ++r) {
        const int row = wr * 32 + (r & 3) + 8 * (r >> 2) + 4 * hi;
        const float nx = rownL[row];
        float d0 = sqrtf(fmaxf(nx + pn0 - 2.f * acc0[r], FEPS));
        float d1 = sqrtf(fmaxf(nx + pn1 - 2.f * acc1[r], FEPS));
        cmin0 = fminf(cmin0, d0);
        cmin1 = fminf(cmin1, d1);
        atomicMin(&rowminL[row], __float_as_uint(fminf(d0, d1)));
    }
    atomicMin(&colminL[p0], __float_as_uint(cmin0));
    atomicMin(&colminL[p1], __float_as_uint(cmin1));
    __syncthreads();

    if (t < 64) {
        float cv = __uint_as_float(rowminL[t]);
        #pragma unroll
        for (int o = 32; o; o >>= 1) cv += __shfl_xor(cv, o);
        if (t == 0) atomicAdd(cov_out, cv);
    }
    if (t < 128) atomicMin(&proto_min[t], colminL[t]);
}

// ---------------- mse body: contiguous chunk, 8-deep MLP, nt loads ----------
__device__ __forceinline__ void mse_body(SmemU& sm, int mb,
                                         const float4* __restrict__ r,
                                         const float4* __restrict__ d,
                                         float* __restrict__ out, int n4) {
    const int t  = threadIdx.x;
    const int CH = (n4 + NB_MSE - 1) / NB_MSE;
    const int base = mb * CH;
    const int L = (base + CH <= n4) ? CH : (n4 - base);
    const f32x4* rb = (const f32x4*)(r + base);
    const f32x4* db = (const f32x4*)(d + base);
    float acc0 = 0.f, acc1 = 0.f, acc2 = 0.f, acc3 = 0.f;
    int k = t;
    for (; k + 7 * 256 < L; k += 8 * 256) {
        f32x4 a0 = __builtin_nontemporal_load(&rb[k + 0 * 256]);
        f32x4 a1 = __builtin_nontemporal_load(&rb[k + 1 * 256]);
        f32x4 a2 = __builtin_nontemporal_load(&rb[k + 2 * 256]);
        f32x4 a3 = __builtin_nontemporal_load(&rb[k + 3 * 256]);
        f32x4 a4 = __builtin_nontemporal_load(&rb[k + 4 * 256]);
        f32x4 a5 = __builtin_nontemporal_load(&rb[k + 5 * 256]);
        f32x4 a6 = __builtin_nontemporal_load(&rb[k + 6 * 256]);
        f32x4 a7 = __builtin_nontemporal_load(&rb[k + 7 * 256]);
        f32x4 b0 = __builtin_nontemporal_load(&db[k + 0 * 256]);
        f32x4 b1 = __builtin_nontemporal_load(&db[k + 1 * 256]);
        f32x4 b2 = __builtin_nontemporal_load(&db[k + 2 * 256]);
        f32x4 b3 = __builtin_nontemporal_load(&db[k + 3 * 256]);
        f32x4 b4 = __builtin_nontemporal_load(&db[k + 4 * 256]);
        f32x4 b5 = __builtin_nontemporal_load(&db[k + 5 * 256]);
        f32x4 b6 = __builtin_nontemporal_load(&db[k + 6 * 256]);
        f32x4 b7 = __builtin_nontemporal_load(&db[k + 7 * 256]);
        f32x4 e;
        e = a0 - b0; acc0 = fmaf(e.x, e.x, acc0); acc1 = fmaf(e.y, e.y, acc1);
                     acc2 = fmaf(e.z, e.z, acc2); acc3 = fmaf(e.w, e.w, acc3);
        e = a1 - b1; acc0 = fmaf(e.x, e.x, acc0); acc1 = fmaf(e.y, e.y, acc1);
                     acc2 = fmaf(e.z, e.z, acc2); acc3 = fmaf(e.w, e.w, acc3);
        e = a2 - b2; acc0 = fmaf(e.x, e.x, acc0); acc1 = fmaf(e.y, e.y, acc1);
                     acc2 = fmaf(e.z, e.z, acc2); acc3 = fmaf(e.w, e.w, acc3);
        e = a3 - b3; acc0 = fmaf(e.x, e.x, acc0); acc1 = fmaf(e.y, e.y, acc1);
                     acc2 = fmaf(e.z, e.z, acc2); acc3 = fmaf(e.w, e.w, acc3);
        e = a4 - b4; acc0 = fmaf(e.x, e.x, acc0); acc1 = fmaf(e.y, e.y, acc1);
                     acc2 = fmaf(e.z, e.z, acc2); acc3 = fmaf(e.w, e.w, acc3);
        e = a5 - b5; acc0 = fmaf(e.x, e.x, acc0); acc1 = fmaf(e.y, e.y, acc1);
                     acc2 = fmaf(e.z, e.z, acc2); acc3 = fmaf(e.w, e.w, acc3);
        e = a6 - b6; acc0 = fmaf(e.x, e.x, acc0); acc1 = fmaf(e.y, e.y, acc1);
                     acc2 = fmaf(e.z, e.z, acc2); acc3 = fmaf(e.w, e.w, acc3);
        e = a7 - b7; acc0 = fmaf(e.x, e.x, acc0); acc1 = fmaf(e.y, e.y, acc1);
                     acc2 = fmaf(e.z, e.z, acc2); acc3 = fmaf(e.w, e.w, acc3);
    }
    for (; k < L; k += 256) {
        f32x4 a = __builtin_nontemporal_load(&rb[k]);
        f32x4 b = __builtin_nontemporal_load(&db[k]);
        f32x4 e = a - b;
        acc0 = fmaf(e.x, e.x, acc0); acc1 = fmaf(e.y, e.y, acc1);
        acc2 = fmaf(e.z, e.z, acc2); acc3 = fmaf(e.w, e.w, acc3);
    }
    float acc = (acc0 + acc1) + (acc2 + acc3);
    #pragma unroll
    for (int o = 32; o; o >>= 1) acc += __shfl_xor(acc, o);
    int lane = t & 63, w = t >> 6;
    if (lane == 0) sm.red.sred[w] = acc;
    __syncthreads();
    if (t == 0) atomicAdd(out, sm.red.sred[0] + sm.red.sred[1]
                             + sm.red.sred[2] + sm.red.sred[3]);
}

// ---------------- ce body ---------------------------------------------------
__device__ __forceinline__ void ce_body(SmemU& sm, int cb,
                                        const float* __restrict__ pred,
                                        const int* __restrict__ lab,
                                        float* __restrict__ ce_out,
                                        int B, int C) {
    const int rows_per_wave = B / (NB_CE * 4);
    int lane = threadIdx.x & 63;
    int w    = threadIdx.x >> 6;
    int wid  = cb * 4 + w;
    float acc = 0.f;
    for (int i = 0; i < rows_per_wave; ++i) {
        int row = wid * rows_per_wave + i;
        const float* p = pred + (size_t)row * C;
        float v1 = (lane < C)      ? p[lane]      : -3.0e38f;
        float v2 = (lane + 64 < C) ? p[lane + 64] : -3.0e38f;
        float m = fmaxf(v1, v2);
        #pragma unroll
        for (int o = 32; o; o >>= 1) m = fmaxf(m, __shfl_xor(m, o));
        float s = ((lane < C) ? __expf(v1 - m) : 0.f)
                + ((lane + 64 < C) ? __expf(v2 - m) : 0.f);
        #pragma unroll
        for (int o = 32; o; o >>= 1) s += __shfl_xor(s, o);
        float lv = p[lab[row]];
        acc += m + __logf(s) - lv;
    }
    if (lane == 0) sm.red.sred[w] = acc;
    __syncthreads();
    if (threadIdx.x == 0) atomicAdd(ce_out, sm.red.sred[0] + sm.red.sred[1]
                                          + sm.red.sred[2] + sm.red.sred[3]);
}

// ---------------- div body --------------------------------------------------
__device__ __forceinline__ void div_body(SmemU& sm, int p,
                                         const float* __restrict__ proto,
                                         float* __restrict__ div_out, int dd) {
    int q = threadIdx.x;
    bool act = q < 128;
    if (act) for (int k = q; k < dd; k += 128) sm.div.pp[k] = proto[(size_t)p * dd + k];
    __syncthreads();
    float dot = 0.f, qq = 0.f;
    if (act) {
        const float4* pq4 = (const float4*)(proto + (size_t)q * dd);
        const float4* pp4 = (const float4*)sm.div.pp;
        for (int k4 = 0; k4 < dd / 4; ++k4) {
            float4 v = pq4[k4];
            float4 u = pp4[k4];
            dot = fmaf(u.x, v.x, dot); dot = fmaf(u.y, v.y, dot);
            dot = fmaf(u.z, v.z, dot); dot = fmaf(u.w, v.w, dot);
            qq  = fmaf(v.x, v.x, qq);  qq  = fmaf(v.y, v.y, qq);
            qq  = fmaf(v.z, v.z, qq);  qq  = fmaf(v.w, v.w, qq);
        }
        if (q == p) sm.div.spp = qq;
    }
    __syncthreads();
    float h2 = 0.f;
    if (act && q > p) {
        float sq = sm.div.spp + qq - 2.f * dot;
        float dist = sqrtf(fmaxf(sq, FEPS));
        float h = fmaxf(0.f, DMIN - dist);
        h2 = h * h;
    }
    #pragma unroll
    for (int o = 32; o; o >>= 1) h2 += __shfl_xor(h2, o);
    if ((q & 63) == 0) sm.div.sred[q >> 6] = h2;
    __syncthreads();
    if (q == 0) atomicAdd(div_out, sm.div.sred[0] + sm.div.sred[1]
                                 + sm.div.sred[2] + sm.div.sred[3]);
}

// ---------------- fused kernel ----------------------------------------------
template<bool PRECONV>
__global__ __launch_bounds__(256) void fused_kernel(
        const float* __restrict__ pred, const int* __restrict__ lab,
        const float4* __restrict__ recon4, const float4* __restrict__ data4,
        const float* __restrict__ emb, const float* __restrict__ proto,
        const ushort_t* __restrict__ pB, const float* __restrict__ pnormG,
        float* __restrict__ ws, unsigned* __restrict__ proto_min,
        int B, int C, int n4, int dd) {
    __shared__ __attribute__((aligned(16))) SmemU sm;
    int bid = blockIdx.x;
    if (bid < NB_DIST) {
        if constexpr (PRECONV) {
            dist_body_fast(sm, bid, emb, pB, pnormG, proto_min, ws + 3);
        } else {
            dist_body_slow(sm, bid * 2, emb, proto, proto_min, ws + 3);
            __syncthreads();
            dist_body_slow(sm, bid * 2 + 1, emb, proto, proto_min, ws + 3);
        }
    } else if (bid < NB_DIST + NB_MSE) {
        mse_body(sm, bid - NB_DIST, recon4, data4, ws + 1, n4);
    } else if (bid < NB_DIST + NB_MSE + NB_CE) {
        ce_body(sm, bid - NB_DIST - NB_MSE, pred, lab, ws + 0, B, C);
    } else {
        div_body(sm, bid - NB_DIST - NB_MSE - NB_CE, proto, ws + 2, dd);
    }
}

// ---------------- final combine ---------------------------------------------
__global__ void final_kernel(const float* __restrict__ ws,
                             const unsigned* __restrict__ pmin,
                             float* __restrict__ out, int B, int D, int P) {
    float sim = 0.f;
    for (int i = 0; i < P; ++i) sim += __uint_as_float(pmin[i]);
    float ce  = ws[0] / (float)B;
    float mse = ws[1] / ((float)B * (float)D);
    out[0] = ce + 0.05f * mse + 0.05f * ws[2] + 0.05f * (sim / (float)P)
           + 0.05f * (ws[3] / (float)B);
}

extern "C" void kernel_launch(void* const* d_in, const int* in_sizes, int n_in,
                              void* d_out, int out_size, void* d_ws, size_t ws_size,
                              hipStream_t stream) {
    const float* pred  = (const float*)d_in[0];
    const float* recon = (const float*)d_in[1];
    const float* data  = (const float*)d_in[2];
    const float* emb   = (const float*)d_in[3];
    const float* proto = (const float*)d_in[4];
    const int*   lab   = (const int*)d_in[5];
    float* out = (float*)d_out;

    int B  = in_sizes[5];            // 32768
    int C  = in_sizes[0] / B;        // 100
    int D  = in_sizes[1] / B;        // 1024
    int dd = in_sizes[3] / B;        // 512
    int P  = in_sizes[4] / dd;       // 128

    float* ws = (float*)d_ws;
    // ws layout: [0]=ce [1]=mse [2]=div [3]=cov ; [4..131]=proto_min bits ;
    //            [132..259]=pnorm ; byte 1280.. : pB bf16 [128][512]
    unsigned* proto_min = (unsigned*)(ws + 4);
    float*    pnorm     = ws + 132;
    ushort_t* pB        = (ushort_t*)((char*)d_ws + 1280);
    bool preconv = ws_size >= (size_t)(1280 + 128 * 512 * 2);

    int n4 = (B * D) / 4;
    int grid = NB_DIST + NB_MSE + NB_CE + NB_DIV;
    if (preconv) {
        conv_kernel<<<128, 128, 0, stream>>>(proto, pB, pnorm, ws, proto_min);
        fused_kernel<true><<<grid, 256, 0, stream>>>(
            pred, lab, (const float4*)recon, (const float4*)data, emb, proto,
            pB, pnorm, ws, proto_min, B, C, n4, dd);
    } else {
        hipMemsetAsync(ws, 0, 4 * sizeof(float), stream);
        hipMemsetAsync(ws + 4, 0x7F, P * sizeof(unsigned), stream);
        fused_kernel<false><<<grid, 256, 0, stream>>>(
            pred, lab, (const float4*)recon, (const float4*)data, emb, proto,
            nullptr, nullptr, ws, proto_min, B, C, n4, dd);
    }
    final_kernel<<<1, 1, 0, stream>>>(ws, proto_min, out, B, D, P);
}